// Round 1
// baseline (608.486 us; speedup 1.0000x reference)
//
#include <hip/hip_runtime.h>
#include <hip/hip_bf16.h>
#include <math.h>

#define NB 4
#define NN 2048
#define ND 64
#define NM 16
#define NK 32
#define EIN 129      // 2*ND+1
#define EH 258       // 2*EIN
#define CHD 64       // 4*NM
#define NHD 128      // 2*ND

__device__ __forceinline__ float silu_f(float x) {
    return x / (1.f + __expf(-x));
}

// ---------------- KNN: one wave per (b,i) row ----------------
__global__ __launch_bounds__(256) void knn_kernel(const float* __restrict__ coors,
                                                  int* __restrict__ idx_out) {
    __shared__ float dist[4][NN];
    const int wv = threadIdx.x >> 6;
    const int lane = threadIdx.x & 63;
    const int row = blockIdx.x * 4 + wv;       // 0..8191
    const int b = row >> 11;
    const int i = row & (NN - 1);
    const float* cb = coors + (size_t)b * NN * 3;
    const float cix = cb[i * 3 + 0], ciy = cb[i * 3 + 1], ciz = cb[i * 3 + 2];
    #pragma unroll 4
    for (int t = 0; t < NN / 64; ++t) {
        int j = lane + 64 * t;
        float dx = cix - cb[j * 3 + 0];
        float dy = ciy - cb[j * 3 + 1];
        float dz = ciz - cb[j * 3 + 2];
        dist[wv][j] = dx * dx + dy * dy + dz * dz;
    }
    __syncthreads();
    int myidx = 0;
    for (int it = 0; it < NK; ++it) {
        float best = 3.4e38f;
        int bj = NN;
        #pragma unroll 4
        for (int t = 0; t < NN / 64; ++t) {
            int j = lane + 64 * t;
            float v = dist[wv][j];
            if (v < best) { best = v; bj = j; }
        }
        #pragma unroll
        for (int off = 1; off < 64; off <<= 1) {
            float ob = __shfl_xor(best, off);
            int oj = __shfl_xor(bj, off);
            if (ob < best || (ob == best && oj < bj)) { best = ob; bj = oj; }
        }
        if (lane == it) myidx = bj;
        if (lane == (bj & 63)) dist[wv][bj] = 3.4e38f;
    }
    if (lane < NK) idx_out[row * NK + lane] = myidx;
}

// ---------------- Edge MLP + coors update + m_i pooling ----------------
// lane = one edge; 64 lanes = 2 nodes * 32 neighbors. Block = 4 waves = 8 nodes.
__global__ __launch_bounds__(256) void edge_kernel(
    const float* __restrict__ feats, const float* __restrict__ coors,
    const int* __restrict__ idx,
    const float* __restrict__ ew1, const float* __restrict__ eb1,
    const float* __restrict__ ew2, const float* __restrict__ eb2,
    const float* __restrict__ cw1, const float* __restrict__ cb1,
    const float* __restrict__ cw2, const float* __restrict__ cb2,
    float* __restrict__ mi_out, float* __restrict__ coors_out) {
    const int lane = threadIdx.x & 63;
    const int wv = threadIdx.x >> 6;
    const int e = lane & 31;
    const int gi = (blockIdx.x * 4 + wv) * 2 + (lane >> 5);  // node 0..8191
    const int b = gi >> 11;
    const int j = idx[gi * NK + e];

    const float* ci = coors + (size_t)gi * 3;
    const float* cj = coors + (size_t)(b * NN + j) * 3;
    const float rx = ci[0] - cj[0], ry = ci[1] - cj[1], rz = ci[2] - cj[2];
    const float dist = rx * rx + ry * ry + rz * rz;

    const float4* fi = (const float4*)(feats + (size_t)gi * ND);
    const float4* fj = (const float4*)(feats + (size_t)(b * NN + j) * ND);

    float m_pre[NM];
    #pragma unroll
    for (int t = 0; t < NM; ++t) m_pre[t] = eb2[t];

    for (int c0 = 0; c0 < EH; c0 += 6) {     // 43 chunks of 6 cols
        float acc[6];
        #pragma unroll
        for (int cc = 0; cc < 6; ++cc) acc[cc] = eb1[c0 + cc];

        auto do64 = [&](const float4* f, const float* wbase) {
            #pragma unroll 4
            for (int k4 = 0; k4 < 16; ++k4) {
                float4 av = f[k4];
                #pragma unroll
                for (int kk = 0; kk < 4; ++kk) {
                    float a = ((const float*)&av)[kk];
                    const float* wr = wbase + (size_t)(k4 * 4 + kk) * EH;
                    #pragma unroll
                    for (int cc = 0; cc < 6; ++cc) acc[cc] += a * wr[cc];
                }
            }
        };
        do64(fi, ew1 + c0);
        do64(fj, ew1 + (size_t)64 * EH + c0);
        {   // dist row (k = 128)
            const float* wr = ew1 + (size_t)128 * EH + c0;
            #pragma unroll
            for (int cc = 0; cc < 6; ++cc) acc[cc] += dist * wr[cc];
        }
        #pragma unroll
        for (int cc = 0; cc < 6; ++cc) {
            float h = silu_f(acc[cc]);
            const float* w2r = ew2 + (size_t)(c0 + cc) * NM;
            #pragma unroll
            for (int t = 0; t < NM; ++t) m_pre[t] += h * w2r[t];
        }
    }

    float m_ij[NM];
    #pragma unroll
    for (int t = 0; t < NM; ++t) m_ij[t] = silu_f(m_pre[t]);

    // coors MLP: 16 -> 64 (silu) -> 1
    float cw_acc = cb2[0];
    #pragma unroll
    for (int g = 0; g < 4; ++g) {
        float chv[16];
        #pragma unroll
        for (int u = 0; u < 16; ++u) chv[u] = cb1[g * 16 + u];
        #pragma unroll
        for (int t = 0; t < NM; ++t) {
            const float* wr = cw1 + (size_t)t * CHD + g * 16;
            #pragma unroll
            for (int u = 0; u < 16; ++u) chv[u] += m_ij[t] * wr[u];
        }
        const float* w2r = cw2 + g * 16;
        #pragma unroll
        for (int u = 0; u < 16; ++u) cw_acc += silu_f(chv[u]) * w2r[u];
    }

    // reduce m_ij over the 32-lane group (neighbor-sum pooling)
    float s[NM];
    #pragma unroll
    for (int t = 0; t < NM; ++t) s[t] = m_ij[t];
    #pragma unroll
    for (int off = 1; off < 32; off <<= 1) {
        #pragma unroll
        for (int t = 0; t < NM; ++t) s[t] += __shfl_xor(s[t], off);
    }
    if (e < NM) mi_out[gi * NM + e] = s[e];

    float wx = cw_acc * rx, wy = cw_acc * ry, wz = cw_acc * rz;
    #pragma unroll
    for (int off = 1; off < 32; off <<= 1) {
        wx += __shfl_xor(wx, off);
        wy += __shfl_xor(wy, off);
        wz += __shfl_xor(wz, off);
    }
    if (e == 0) {
        coors_out[gi * 3 + 0] = ci[0] + wx;
        coors_out[gi * 3 + 1] = ci[1] + wy;
        coors_out[gi * 3 + 2] = ci[2] + wz;
    }
}

// ---------------- Node MLP: wave per node ----------------
__global__ __launch_bounds__(256) void node_kernel(
    const float* __restrict__ feats, const float* __restrict__ mi,
    const float* __restrict__ nw1, const float* __restrict__ nb1,
    const float* __restrict__ nw2, const float* __restrict__ nb2,
    float* __restrict__ node_out) {
    __shared__ float hbuf[4][NHD];
    const int wv = threadIdx.x >> 6;
    const int lane = threadIdx.x & 63;
    const int gi = blockIdx.x * 4 + wv;
    const float* fi = feats + (size_t)gi * ND;
    float a0 = nb1[lane], a1 = nb1[64 + lane];
    #pragma unroll 4
    for (int k = 0; k < ND; ++k) {
        float a = fi[k];
        a0 += a * nw1[(size_t)k * NHD + lane];
        a1 += a * nw1[(size_t)k * NHD + 64 + lane];
    }
    #pragma unroll
    for (int k = 0; k < NM; ++k) {
        float a = mi[gi * NM + k];
        a0 += a * nw1[(size_t)(ND + k) * NHD + lane];
        a1 += a * nw1[(size_t)(ND + k) * NHD + 64 + lane];
    }
    hbuf[wv][lane] = silu_f(a0);
    hbuf[wv][64 + lane] = silu_f(a1);
    __syncthreads();
    float o = nb2[lane];
    #pragma unroll 4
    for (int k = 0; k < NHD; ++k) o += hbuf[wv][k] * nw2[(size_t)k * ND + lane];
    node_out[(size_t)gi * ND + lane] = o + fi[lane];
}

extern "C" void kernel_launch(void* const* d_in, const int* in_sizes, int n_in,
                              void* d_out, int out_size, void* d_ws, size_t ws_size,
                              hipStream_t stream) {
    const float* feats = (const float*)d_in[0];
    const float* coors = (const float*)d_in[1];
    const float* ew1 = (const float*)d_in[2];
    const float* eb1 = (const float*)d_in[3];
    const float* ew2 = (const float*)d_in[4];
    const float* eb2 = (const float*)d_in[5];
    const float* cw1 = (const float*)d_in[6];
    const float* cb1 = (const float*)d_in[7];
    const float* cw2 = (const float*)d_in[8];
    const float* cb2 = (const float*)d_in[9];
    const float* nw1 = (const float*)d_in[10];
    const float* nb1 = (const float*)d_in[11];
    const float* nw2 = (const float*)d_in[12];
    const float* nb2 = (const float*)d_in[13];

    float* out_node = (float*)d_out;                     // [4,2048,64]
    float* out_coors = out_node + (size_t)NB * NN * ND;  // [4,2048,3]

    int* idx = (int*)d_ws;                                           // 8192*32 ints
    float* mi = (float*)((char*)d_ws + (size_t)NB * NN * NK * sizeof(int));  // 8192*16 f32

    knn_kernel<<<NB * NN / 4, 256, 0, stream>>>(coors, idx);
    edge_kernel<<<NB * NN / 8, 256, 0, stream>>>(feats, coors, idx, ew1, eb1, ew2,
                                                 eb2, cw1, cb1, cw2, cb2, mi, out_coors);
    node_kernel<<<NB * NN / 4, 256, 0, stream>>>(feats, mi, nw1, nb1, nw2, nb2, out_node);
}

// Round 2
// 274.192 us; speedup vs baseline: 2.2192x; 2.2192x over previous
//
#include <hip/hip_runtime.h>
#include <hip/hip_bf16.h>
#include <math.h>

#define NB 4
#define NN 2048
#define ND 64
#define NM 16
#define NK 32
#define EIN 129      // 2*ND+1
#define EH 258       // 2*EIN
#define CHD 64       // 4*NM
#define NHD 128      // 2*ND
#define PQS 260      // padded row stride for P/Q (1040B, 16B-aligned)

__device__ __forceinline__ float silu_f(float x) {
    return x / (1.f + __expf(-x));
}

// ---------------- KNN: one wave per (b,i) row ----------------
__global__ __launch_bounds__(256) void knn_kernel(const float* __restrict__ coors,
                                                  int* __restrict__ idx_out) {
    __shared__ float dist[4][NN];
    const int wv = threadIdx.x >> 6;
    const int lane = threadIdx.x & 63;
    const int row = blockIdx.x * 4 + wv;       // 0..8191
    const int b = row >> 11;
    const int i = row & (NN - 1);
    const float* cb = coors + (size_t)b * NN * 3;
    const float cix = cb[i * 3 + 0], ciy = cb[i * 3 + 1], ciz = cb[i * 3 + 2];
    #pragma unroll 4
    for (int t = 0; t < NN / 64; ++t) {
        int j = lane + 64 * t;
        float dx = cix - cb[j * 3 + 0];
        float dy = ciy - cb[j * 3 + 1];
        float dz = ciz - cb[j * 3 + 2];
        dist[wv][j] = dx * dx + dy * dy + dz * dz;
    }
    __syncthreads();
    int myidx = 0;
    for (int it = 0; it < NK; ++it) {
        float best = 3.4e38f;
        int bj = NN;
        #pragma unroll 4
        for (int t = 0; t < NN / 64; ++t) {
            int j = lane + 64 * t;
            float v = dist[wv][j];
            if (v < best) { best = v; bj = j; }
        }
        #pragma unroll
        for (int off = 1; off < 64; off <<= 1) {
            float ob = __shfl_xor(best, off);
            int oj = __shfl_xor(bj, off);
            if (ob < best || (ob == best && oj < bj)) { best = ob; bj = oj; }
        }
        if (lane == it) myidx = bj;
        if (lane == (bj & 63)) dist[wv][bj] = 3.4e38f;
    }
    if (lane < NK) idx_out[row * NK + lane] = myidx;
}

// ---------------- Precompute P = feats@W1a + b1, Q = feats@W1b ----------------
// One wave per node; lane handles cols {lane, lane+64, lane+128, lane+192, lane+256}.
__global__ __launch_bounds__(256) void pq_kernel(const float* __restrict__ feats,
                                                 const float* __restrict__ ew1,
                                                 const float* __restrict__ eb1,
                                                 float* __restrict__ P,
                                                 float* __restrict__ Q) {
    __shared__ float sf[4][ND];
    const int wv = threadIdx.x >> 6;
    const int lane = threadIdx.x & 63;
    const int gi = blockIdx.x * 4 + wv;
    sf[wv][lane] = feats[(size_t)gi * ND + lane];
    __syncthreads();
    float accP[5] = {0.f, 0.f, 0.f, 0.f, 0.f};
    float accQ[5] = {0.f, 0.f, 0.f, 0.f, 0.f};
    #pragma unroll 4
    for (int k = 0; k < ND; ++k) {
        float a = sf[wv][k];
        const float* wa = ew1 + (size_t)k * EH + lane;
        const float* wb = ew1 + (size_t)(k + 64) * EH + lane;
        #pragma unroll
        for (int t = 0; t < 5; ++t) {
            int c = lane + 64 * t;
            if (c < EH) {
                accP[t] += a * wa[64 * t];
                accQ[t] += a * wb[64 * t];
            }
        }
    }
    float* Pr = P + (size_t)gi * PQS;
    float* Qr = Q + (size_t)gi * PQS;
    #pragma unroll
    for (int t = 0; t < 5; ++t) {
        int c = lane + 64 * t;
        if (c < EH) {
            Pr[c] = accP[t] + eb1[c];
            Qr[c] = accQ[t];
        }
    }
}

// ---------------- Edge: h=silu(P[i]+Q[j]+dist*w1c), MLP2, coors, pooling ----------------
// lane = one edge; 64 lanes = 2 nodes * 32 neighbors. Block = 4 waves = 8 nodes.
__global__ __launch_bounds__(256) void edge_kernel(
    const float* __restrict__ coors, const int* __restrict__ idx,
    const float* __restrict__ P, const float* __restrict__ Q,
    const float* __restrict__ ew1,
    const float* __restrict__ ew2, const float* __restrict__ eb2,
    const float* __restrict__ cw1, const float* __restrict__ cb1,
    const float* __restrict__ cw2, const float* __restrict__ cb2,
    float* __restrict__ mi_out, float* __restrict__ coors_out) {
    const int lane = threadIdx.x & 63;
    const int wv = threadIdx.x >> 6;
    const int e = lane & 31;
    const int gi = (blockIdx.x * 4 + wv) * 2 + (lane >> 5);  // node 0..8191
    const int b = gi >> 11;
    const int j = idx[gi * NK + e];

    const float* ci = coors + (size_t)gi * 3;
    const float* cj = coors + (size_t)(b * NN + j) * 3;
    const float rx = ci[0] - cj[0], ry = ci[1] - cj[1], rz = ci[2] - cj[2];
    const float dist = rx * rx + ry * ry + rz * rz;

    const float4* Pr = (const float4*)(P + (size_t)gi * PQS);
    const float4* Qr = (const float4*)(Q + (size_t)(b * NN + j) * PQS);
    const float* w1c = ew1 + (size_t)128 * EH;

    float m_pre[NM];
    #pragma unroll
    for (int t = 0; t < NM; ++t) m_pre[t] = eb2[t];

    #pragma unroll 4
    for (int ch = 0; ch < 64; ++ch) {     // cols 0..255 in float4 chunks
        float4 pv = Pr[ch];
        float4 qv = Qr[ch];
        const int c0 = ch * 4;
        #pragma unroll
        for (int cc = 0; cc < 4; ++cc) {
            float h = silu_f(((const float*)&pv)[cc] + ((const float*)&qv)[cc]
                             + dist * w1c[c0 + cc]);
            const float* w2r = ew2 + (size_t)(c0 + cc) * NM;
            #pragma unroll
            for (int t = 0; t < NM; ++t) m_pre[t] += h * w2r[t];
        }
    }
    #pragma unroll
    for (int c = 256; c < EH; ++c) {      // remainder cols
        float h = silu_f(((const float*)Pr)[c] + ((const float*)Qr)[c] + dist * w1c[c]);
        const float* w2r = ew2 + (size_t)c * NM;
        #pragma unroll
        for (int t = 0; t < NM; ++t) m_pre[t] += h * w2r[t];
    }

    float m_ij[NM];
    #pragma unroll
    for (int t = 0; t < NM; ++t) m_ij[t] = silu_f(m_pre[t]);

    // coors MLP: 16 -> 64 (silu) -> 1
    float cw_acc = cb2[0];
    #pragma unroll
    for (int g = 0; g < 4; ++g) {
        float chv[16];
        #pragma unroll
        for (int u = 0; u < 16; ++u) chv[u] = cb1[g * 16 + u];
        #pragma unroll
        for (int t = 0; t < NM; ++t) {
            const float* wr = cw1 + (size_t)t * CHD + g * 16;
            #pragma unroll
            for (int u = 0; u < 16; ++u) chv[u] += m_ij[t] * wr[u];
        }
        const float* w2r = cw2 + g * 16;
        #pragma unroll
        for (int u = 0; u < 16; ++u) cw_acc += silu_f(chv[u]) * w2r[u];
    }

    // reduce m_ij over the 32-lane group (neighbor-sum pooling)
    float s[NM];
    #pragma unroll
    for (int t = 0; t < NM; ++t) s[t] = m_ij[t];
    #pragma unroll
    for (int off = 1; off < 32; off <<= 1) {
        #pragma unroll
        for (int t = 0; t < NM; ++t) s[t] += __shfl_xor(s[t], off);
    }
    if (e < NM) mi_out[gi * NM + e] = s[e];

    float wx = cw_acc * rx, wy = cw_acc * ry, wz = cw_acc * rz;
    #pragma unroll
    for (int off = 1; off < 32; off <<= 1) {
        wx += __shfl_xor(wx, off);
        wy += __shfl_xor(wy, off);
        wz += __shfl_xor(wz, off);
    }
    if (e == 0) {
        coors_out[gi * 3 + 0] = ci[0] + wx;
        coors_out[gi * 3 + 1] = ci[1] + wy;
        coors_out[gi * 3 + 2] = ci[2] + wz;
    }
}

// ---------------- Node MLP: wave per node ----------------
__global__ __launch_bounds__(256) void node_kernel(
    const float* __restrict__ feats, const float* __restrict__ mi,
    const float* __restrict__ nw1, const float* __restrict__ nb1,
    const float* __restrict__ nw2, const float* __restrict__ nb2,
    float* __restrict__ node_out) {
    __shared__ float hbuf[4][NHD];
    const int wv = threadIdx.x >> 6;
    const int lane = threadIdx.x & 63;
    const int gi = blockIdx.x * 4 + wv;
    const float* fi = feats + (size_t)gi * ND;
    float a0 = nb1[lane], a1 = nb1[64 + lane];
    #pragma unroll 4
    for (int k = 0; k < ND; ++k) {
        float a = fi[k];
        a0 += a * nw1[(size_t)k * NHD + lane];
        a1 += a * nw1[(size_t)k * NHD + 64 + lane];
    }
    #pragma unroll
    for (int k = 0; k < NM; ++k) {
        float a = mi[gi * NM + k];
        a0 += a * nw1[(size_t)(ND + k) * NHD + lane];
        a1 += a * nw1[(size_t)(ND + k) * NHD + 64 + lane];
    }
    hbuf[wv][lane] = silu_f(a0);
    hbuf[wv][64 + lane] = silu_f(a1);
    __syncthreads();
    float o = nb2[lane];
    #pragma unroll 4
    for (int k = 0; k < NHD; ++k) o += hbuf[wv][k] * nw2[(size_t)k * ND + lane];
    node_out[(size_t)gi * ND + lane] = o + fi[lane];
}

extern "C" void kernel_launch(void* const* d_in, const int* in_sizes, int n_in,
                              void* d_out, int out_size, void* d_ws, size_t ws_size,
                              hipStream_t stream) {
    const float* feats = (const float*)d_in[0];
    const float* coors = (const float*)d_in[1];
    const float* ew1 = (const float*)d_in[2];
    const float* eb1 = (const float*)d_in[3];
    const float* ew2 = (const float*)d_in[4];
    const float* eb2 = (const float*)d_in[5];
    const float* cw1 = (const float*)d_in[6];
    const float* cb1 = (const float*)d_in[7];
    const float* cw2 = (const float*)d_in[8];
    const float* cb2 = (const float*)d_in[9];
    const float* nw1 = (const float*)d_in[10];
    const float* nb1 = (const float*)d_in[11];
    const float* nw2 = (const float*)d_in[12];
    const float* nb2 = (const float*)d_in[13];

    float* out_node = (float*)d_out;                     // [4,2048,64]
    float* out_coors = out_node + (size_t)NB * NN * ND;  // [4,2048,3]

    char* ws = (char*)d_ws;
    int* idx = (int*)ws;                                  // 8192*32*4 = 1 MB
    float* mi = (float*)(ws + 1048576);                   // 8192*16*4 = 0.5 MB
    float* P  = (float*)(ws + 1572864);                   // 8192*260*4 = 8.52 MB
    float* Q  = (float*)(ws + 10092544);                  // 8192*260*4 = 8.52 MB

    knn_kernel<<<NB * NN / 4, 256, 0, stream>>>(coors, idx);
    pq_kernel<<<NB * NN / 4, 256, 0, stream>>>(feats, ew1, eb1, P, Q);
    edge_kernel<<<NB * NN / 8, 256, 0, stream>>>(coors, idx, P, Q, ew1, ew2, eb2,
                                                 cw1, cb1, cw2, cb2, mi, out_coors);
    node_kernel<<<NB * NN / 4, 256, 0, stream>>>(feats, mi, nw1, nb1, nw2, nb2, out_node);
}

// Round 3
// 248.555 us; speedup vs baseline: 2.4481x; 1.1031x over previous
//
#include <hip/hip_runtime.h>
#include <math.h>

#define NB 4
#define NN 2048
#define ND 64
#define NM 16
#define NK 32
#define EIN 129      // 2*ND+1
#define EH 258       // 2*EIN
#define CHD 64       // 4*NM
#define NHD 128      // 2*ND
#define PQS 288      // padded row stride for P/Q (zero-filled 258..287) = 9*32

typedef __attribute__((ext_vector_type(8))) short short8;
typedef __attribute__((ext_vector_type(4))) float f32x4;

__device__ __forceinline__ float silu_f(float x) {
    return x / (1.f + __expf(-x));
}

__device__ __forceinline__ short f2bf(float f) {   // RNE float->bf16
    union { float f; unsigned u; } v; v.f = f;
    unsigned r = v.u + 0x7FFFu + ((v.u >> 16) & 1u);
    return (short)(r >> 16);
}

// ---------------- KNN v2: packed keys + per-lane bitonic sort ----------------
// wave = one (b,i) row. key = (bits(d) & ~0x7FF) | j  (uint order == (d,j) lex order
// modulo 11-bit truncation; ties at <2^-21 relative distance are output-negligible).
__global__ __launch_bounds__(256) void knn_kernel(const float* __restrict__ coors,
                                                  int* __restrict__ idx_out) {
    __shared__ unsigned slds[4][NN];
    const int wv = threadIdx.x >> 6;
    const int lane = threadIdx.x & 63;
    const int row = blockIdx.x * 4 + wv;       // 0..8191
    const int b = row >> 11;
    const int i = row & (NN - 1);
    const float* cb = coors + (size_t)b * NN * 3;
    const float cix = cb[i * 3 + 0], ciy = cb[i * 3 + 1], ciz = cb[i * 3 + 2];

    unsigned k[32];
    #pragma unroll
    for (int t = 0; t < 32; ++t) {
        int j = lane + 64 * t;
        float dx = cix - cb[j * 3 + 0];
        float dy = ciy - cb[j * 3 + 1];
        float dz = ciz - cb[j * 3 + 2];
        float d = dx * dx + dy * dy + dz * dz;
        union { float f; unsigned u; } v; v.f = d;
        k[t] = (v.u & 0xFFFFF800u) | (unsigned)j;
    }
    // in-register bitonic sort (ascending), static indices only
    #pragma unroll
    for (int size = 2; size <= 32; size <<= 1) {
        #pragma unroll
        for (int stride = size >> 1; stride > 0; stride >>= 1) {
            #pragma unroll
            for (int t = 0; t < 32; ++t) {
                int p = t ^ stride;
                if (p > t) {
                    bool up = ((t & size) == 0);
                    unsigned lo = k[t] < k[p] ? k[t] : k[p];
                    unsigned hi = k[t] < k[p] ? k[p] : k[t];
                    k[t] = up ? lo : hi;
                    k[p] = up ? hi : lo;
                }
            }
        }
    }
    #pragma unroll
    for (int t = 0; t < 32; ++t) slds[wv][t * 64 + lane] = k[t];

    unsigned cur = k[0];
    int head = 0;
    int myidx = 0;
    for (int it = 0; it < NK; ++it) {
        unsigned w = cur;
        #pragma unroll
        for (int off = 1; off < 64; off <<= 1) {
            unsigned o = __shfl_xor(w, off);
            w = o < w ? o : w;
        }
        if (lane == it) myidx = (int)(w & 2047u);
        if (cur == w) {   // unique winner (j bits distinct)
            ++head;
            cur = (head < 32) ? slds[wv][head * 64 + lane] : 0xFFFFFFFFu;
        }
    }
    if (lane < NK) idx_out[row * NK + lane] = myidx;
}

// ---------------- Precompute P = feats@W1a + b1, Q = feats@W1b (zero-padded) ----------------
__global__ __launch_bounds__(256) void pq_kernel(const float* __restrict__ feats,
                                                 const float* __restrict__ ew1,
                                                 const float* __restrict__ eb1,
                                                 float* __restrict__ P,
                                                 float* __restrict__ Q) {
    __shared__ float sf[4][ND];
    const int wv = threadIdx.x >> 6;
    const int lane = threadIdx.x & 63;
    const int gi = blockIdx.x * 4 + wv;
    sf[wv][lane] = feats[(size_t)gi * ND + lane];
    __syncthreads();
    float accP[5] = {0.f, 0.f, 0.f, 0.f, 0.f};
    float accQ[5] = {0.f, 0.f, 0.f, 0.f, 0.f};
    #pragma unroll 4
    for (int kx = 0; kx < ND; ++kx) {
        float a = sf[wv][kx];
        const float* wa = ew1 + (size_t)kx * EH + lane;
        const float* wb = ew1 + (size_t)(kx + 64) * EH + lane;
        #pragma unroll
        for (int t = 0; t < 5; ++t) {
            int c = lane + 64 * t;
            if (c < EH) {
                accP[t] += a * wa[64 * t];
                accQ[t] += a * wb[64 * t];
            }
        }
    }
    float* Pr = P + (size_t)gi * PQS;
    float* Qr = Q + (size_t)gi * PQS;
    #pragma unroll
    for (int t = 0; t < 5; ++t) {
        int c = lane + 64 * t;
        if (c < PQS) {
            Pr[c] = (c < EH) ? accP[t] + eb1[c] : 0.f;
            Qr[c] = (c < EH) ? accQ[t] : 0.f;
        }
    }
}

// ---------------- Edge: MFMA MLP2 + coors MLP + pooling. wave = 1 node (32 edges) ----------------
__global__ __launch_bounds__(256) void edge_kernel(
    const float* __restrict__ coors, const int* __restrict__ idx,
    const float* __restrict__ P, const float* __restrict__ Q,
    const float* __restrict__ ew1,
    const float* __restrict__ ew2, const float* __restrict__ eb2,
    const float* __restrict__ cw1, const float* __restrict__ cb1,
    const float* __restrict__ cw2, const float* __restrict__ cb2,
    float* __restrict__ mi_out, float* __restrict__ coors_out) {

    __shared__ float w1lds[PQS];          // w1c zero-padded
    __shared__ float w2lds[PQS * NM];     // W2 zero-padded rows 258..287
    __shared__ float mlds[4][NM][NK];     // [wave][t][edge]

    const int tid = threadIdx.x;
    for (int t = tid; t < PQS * NM; t += 256) w2lds[t] = (t < EH * NM) ? ew2[t] : 0.f;
    if (tid < PQS) w1lds[tid] = (tid < EH) ? ew1[128 * EH + tid] : 0.f;
    __syncthreads();

    const int wv = tid >> 6, lane = tid & 63;
    const int er = lane & 15, grp = lane >> 4;
    const int gi = blockIdx.x * 4 + wv;      // node 0..8191
    const int b = gi >> 11;

    const float ci0 = coors[gi * 3 + 0], ci1 = coors[gi * 3 + 1], ci2 = coors[gi * 3 + 2];

    // B fragments: W2[k][t], k = kk*32 + grp*8 + i, col t = er
    short8 bfrag[9];
    #pragma unroll
    for (int kk = 0; kk < 9; ++kk) {
        #pragma unroll
        for (int i = 0; i < 8; ++i)
            bfrag[kk][i] = f2bf(w2lds[(kk * 32 + grp * 8 + i) * NM + er]);
    }

    const f32x4* Pr4 = (const f32x4*)(P + (size_t)gi * PQS);
    const f32x4* w14 = (const f32x4*)w1lds;

    f32x4 accT[2];
    #pragma unroll
    for (int T = 0; T < 2; ++T) {
        const int eA = T * 16 + er;                    // A-row edge
        const int jA = idx[gi * NK + eA];
        const float* cj = coors + (size_t)(b * NN + jA) * 3;
        const float dx = ci0 - cj[0], dy = ci1 - cj[1], dz = ci2 - cj[2];
        const float dA = dx * dx + dy * dy + dz * dz;
        const f32x4* Qr4 = (const f32x4*)(Q + (size_t)(b * NN + jA) * PQS);
        f32x4 acc = {0.f, 0.f, 0.f, 0.f};
        #pragma unroll
        for (int kk = 0; kk < 9; ++kk) {
            const int fb = kk * 8 + grp * 2;
            f32x4 p0 = Pr4[fb], p1 = Pr4[fb + 1];
            f32x4 q0 = Qr4[fb], q1 = Qr4[fb + 1];
            f32x4 w0 = w14[fb], w1 = w14[fb + 1];
            short8 af;
            af[0] = f2bf(silu_f(p0[0] + q0[0] + dA * w0[0]));
            af[1] = f2bf(silu_f(p0[1] + q0[1] + dA * w0[1]));
            af[2] = f2bf(silu_f(p0[2] + q0[2] + dA * w0[2]));
            af[3] = f2bf(silu_f(p0[3] + q0[3] + dA * w0[3]));
            af[4] = f2bf(silu_f(p1[0] + q1[0] + dA * w1[0]));
            af[5] = f2bf(silu_f(p1[1] + q1[1] + dA * w1[1]));
            af[6] = f2bf(silu_f(p1[2] + q1[2] + dA * w1[2]));
            af[7] = f2bf(silu_f(p1[3] + q1[3] + dA * w1[3]));
            acc = __builtin_amdgcn_mfma_f32_16x16x32_bf16(af, bfrag[kk], acc, 0, 0, 0);
        }
        accT[T] = acc;
    }

    // lane holds m_pre[edge = T*16 + grp*4 + r][t = er]
    const float eb2v = eb2[er];
    float m0[4], m1[4];
    #pragma unroll
    for (int r = 0; r < 4; ++r) {
        m0[r] = silu_f(accT[0][r] + eb2v);
        m1[r] = silu_f(accT[1][r] + eb2v);
    }

    // m_i pooling: sum over all 32 edges for output t = er
    float s = m0[0] + m0[1] + m0[2] + m0[3] + m1[0] + m1[1] + m1[2] + m1[3];
    s += __shfl_xor(s, 16);
    s += __shfl_xor(s, 32);
    if (lane < NM) mi_out[gi * NM + er] = s;

    // transpose to [t][edge] for coors MLP
    #pragma unroll
    for (int r = 0; r < 4; ++r) {
        mlds[wv][er][grp * 4 + r] = m0[r];
        mlds[wv][er][16 + grp * 4 + r] = m1[r];
    }
    __syncthreads();

    // coors MLP: 2 lanes per edge (half = lane>>5), each does 32 of 64 hidden
    const int e2 = lane & 31, half = lane >> 5;
    const int j2 = idx[gi * NK + e2];
    const float* cj2 = coors + (size_t)(b * NN + j2) * 3;
    const float rx = ci0 - cj2[0], ry = ci1 - cj2[1], rz = ci2 - cj2[2];

    float m[16];
    #pragma unroll
    for (int t = 0; t < 16; ++t) m[t] = mlds[wv][t][e2];

    float a[32];
    const f32x4* cb1v = (const f32x4*)(cb1 + half * 32);
    #pragma unroll
    for (int q = 0; q < 8; ++q) {
        f32x4 v = cb1v[q];
        a[q * 4 + 0] = v[0]; a[q * 4 + 1] = v[1]; a[q * 4 + 2] = v[2]; a[q * 4 + 3] = v[3];
    }
    #pragma unroll
    for (int t = 0; t < 16; ++t) {
        const f32x4* w = (const f32x4*)(cw1 + t * CHD + half * 32);
        #pragma unroll
        for (int q = 0; q < 8; ++q) {
            f32x4 v = w[q];
            a[q * 4 + 0] += m[t] * v[0];
            a[q * 4 + 1] += m[t] * v[1];
            a[q * 4 + 2] += m[t] * v[2];
            a[q * 4 + 3] += m[t] * v[3];
        }
    }
    float cwacc = 0.f;
    const f32x4* cw2v = (const f32x4*)(cw2 + half * 32);
    #pragma unroll
    for (int q = 0; q < 8; ++q) {
        f32x4 v = cw2v[q];
        cwacc += silu_f(a[q * 4 + 0]) * v[0] + silu_f(a[q * 4 + 1]) * v[1]
               + silu_f(a[q * 4 + 2]) * v[2] + silu_f(a[q * 4 + 3]) * v[3];
    }
    cwacc += __shfl_xor(cwacc, 32);      // join the two halves
    cwacc += cb2[0];
    float wx = cwacc * rx, wy = cwacc * ry, wz = cwacc * rz;
    #pragma unroll
    for (int off = 1; off < 32; off <<= 1) {
        wx += __shfl_xor(wx, off);
        wy += __shfl_xor(wy, off);
        wz += __shfl_xor(wz, off);
    }
    if (lane == 0) {
        coors_out[gi * 3 + 0] = ci0 + wx;
        coors_out[gi * 3 + 1] = ci1 + wy;
        coors_out[gi * 3 + 2] = ci2 + wz;
    }
}

// ---------------- Node MLP: wave per node ----------------
__global__ __launch_bounds__(256) void node_kernel(
    const float* __restrict__ feats, const float* __restrict__ mi,
    const float* __restrict__ nw1, const float* __restrict__ nb1,
    const float* __restrict__ nw2, const float* __restrict__ nb2,
    float* __restrict__ node_out) {
    __shared__ float hbuf[4][NHD];
    const int wv = threadIdx.x >> 6;
    const int lane = threadIdx.x & 63;
    const int gi = blockIdx.x * 4 + wv;
    const float* fi = feats + (size_t)gi * ND;
    float a0 = nb1[lane], a1 = nb1[64 + lane];
    #pragma unroll 4
    for (int k = 0; k < ND; ++k) {
        float a = fi[k];
        a0 += a * nw1[(size_t)k * NHD + lane];
        a1 += a * nw1[(size_t)k * NHD + 64 + lane];
    }
    #pragma unroll
    for (int k = 0; k < NM; ++k) {
        float a = mi[gi * NM + k];
        a0 += a * nw1[(size_t)(ND + k) * NHD + lane];
        a1 += a * nw1[(size_t)(ND + k) * NHD + 64 + lane];
    }
    hbuf[wv][lane] = silu_f(a0);
    hbuf[wv][64 + lane] = silu_f(a1);
    __syncthreads();
    float o = nb2[lane];
    #pragma unroll 4
    for (int k = 0; k < NHD; ++k) o += hbuf[wv][k] * nw2[(size_t)k * ND + lane];
    node_out[(size_t)gi * ND + lane] = o + fi[lane];
}

extern "C" void kernel_launch(void* const* d_in, const int* in_sizes, int n_in,
                              void* d_out, int out_size, void* d_ws, size_t ws_size,
                              hipStream_t stream) {
    const float* feats = (const float*)d_in[0];
    const float* coors = (const float*)d_in[1];
    const float* ew1 = (const float*)d_in[2];
    const float* eb1 = (const float*)d_in[3];
    const float* ew2 = (const float*)d_in[4];
    const float* eb2 = (const float*)d_in[5];
    const float* cw1 = (const float*)d_in[6];
    const float* cb1 = (const float*)d_in[7];
    const float* cw2 = (const float*)d_in[8];
    const float* cb2 = (const float*)d_in[9];
    const float* nw1 = (const float*)d_in[10];
    const float* nb1 = (const float*)d_in[11];
    const float* nw2 = (const float*)d_in[12];
    const float* nb2 = (const float*)d_in[13];

    float* out_node = (float*)d_out;                     // [4,2048,64]
    float* out_coors = out_node + (size_t)NB * NN * ND;  // [4,2048,3]

    char* ws = (char*)d_ws;
    int* idx = (int*)ws;                                  // 8192*32*4 = 1 MB
    float* mi = (float*)(ws + 1048576);                   // 8192*16*4 = 0.5 MB
    float* P  = (float*)(ws + 1572864);                   // 8192*288*4 = 9.44 MB
    float* Q  = (float*)(ws + 11010048);                  // 8192*288*4 = 9.44 MB

    knn_kernel<<<NB * NN / 4, 256, 0, stream>>>(coors, idx);
    pq_kernel<<<NB * NN / 4, 256, 0, stream>>>(feats, ew1, eb1, P, Q);
    edge_kernel<<<NB * NN / 4, 256, 0, stream>>>(coors, idx, P, Q, ew1, ew2, eb2,
                                                 cw1, cb1, cw2, cb2, mi, out_coors);
    node_kernel<<<NB * NN / 4, 256, 0, stream>>>(feats, mi, nw1, nb1, nw2, nb2, out_node);
}

// Round 4
// 178.218 us; speedup vs baseline: 3.4143x; 1.3947x over previous
//
#include <hip/hip_runtime.h>
#include <math.h>

#define NB 4
#define NN 2048
#define ND 64
#define NM 16
#define NK 32
#define EIN 129      // 2*ND+1
#define EH 258       // 2*EIN
#define CHD 64       // 4*NM
#define NHD 128      // 2*ND
#define PQS 288      // padded K for MFMA (zero-filled 258..287) = 9*32

typedef __attribute__((ext_vector_type(8))) short short8;
typedef __attribute__((ext_vector_type(4))) float f32x4;

__device__ __forceinline__ float silu_f(float x) {
    return x / (1.f + __expf(-x));
}

__device__ __forceinline__ short f2bf(float f) {   // RNE float->bf16
    union { float f; unsigned u; } v; v.f = f;
    unsigned r = v.u + 0x7FFFu + ((v.u >> 16) & 1u);
    return (short)(r >> 16);
}

__device__ __forceinline__ float bf2f(short s) {
    union { unsigned u; float f; } v;
    v.u = ((unsigned)(unsigned short)s) << 16;
    return v.f;
}

// ---------------- prep: W2T[t][k] bf16 (zero-padded), w1pad f32 ----------------
__global__ void prep_kernel(const float* __restrict__ ew1, const float* __restrict__ ew2,
                            float* __restrict__ w1pad, short* __restrict__ W2T) {
    const int tid = threadIdx.x;
    for (int k = tid; k < PQS; k += 256)
        w1pad[k] = (k < EH) ? ew1[128 * EH + k] : 0.f;
    for (int t = 0; t < NM; ++t)
        for (int k = tid; k < PQS; k += 256)
            W2T[t * PQS + k] = (k < EH) ? f2bf(ew2[k * NM + t]) : (short)0;
}

// ---------------- KNN: packed keys + per-lane bitonic sort; exports dist ----------------
__global__ __launch_bounds__(256) void knn_kernel(const float* __restrict__ coors,
                                                  int* __restrict__ idx_out,
                                                  float* __restrict__ dist_out) {
    __shared__ unsigned slds[4][NN];
    const int wv = threadIdx.x >> 6;
    const int lane = threadIdx.x & 63;
    const int row = blockIdx.x * 4 + wv;       // 0..8191
    const int b = row >> 11;
    const int i = row & (NN - 1);
    const float* cb = coors + (size_t)b * NN * 3;
    const float cix = cb[i * 3 + 0], ciy = cb[i * 3 + 1], ciz = cb[i * 3 + 2];

    unsigned k[32];
    #pragma unroll
    for (int t = 0; t < 32; ++t) {
        int j = lane + 64 * t;
        float dx = cix - cb[j * 3 + 0];
        float dy = ciy - cb[j * 3 + 1];
        float dz = ciz - cb[j * 3 + 2];
        float d = dx * dx + dy * dy + dz * dz;
        union { float f; unsigned u; } v; v.f = d;
        k[t] = (v.u & 0xFFFFF800u) | (unsigned)j;
    }
    #pragma unroll
    for (int size = 2; size <= 32; size <<= 1) {
        #pragma unroll
        for (int stride = size >> 1; stride > 0; stride >>= 1) {
            #pragma unroll
            for (int t = 0; t < 32; ++t) {
                int p = t ^ stride;
                if (p > t) {
                    bool up = ((t & size) == 0);
                    unsigned lo = k[t] < k[p] ? k[t] : k[p];
                    unsigned hi = k[t] < k[p] ? k[p] : k[t];
                    k[t] = up ? lo : hi;
                    k[p] = up ? hi : lo;
                }
            }
        }
    }
    #pragma unroll
    for (int t = 0; t < 32; ++t) slds[wv][t * 64 + lane] = k[t];

    unsigned cur = k[0];
    int head = 0;
    int myidx = 0;
    unsigned mykey = 0;
    for (int it = 0; it < NK; ++it) {
        unsigned w = cur;
        #pragma unroll
        for (int off = 1; off < 64; off <<= 1) {
            unsigned o = __shfl_xor(w, off);
            w = o < w ? o : w;
        }
        if (lane == it) { myidx = (int)(w & 2047u); mykey = w & 0xFFFFF800u; }
        if (cur == w) {
            ++head;
            cur = (head < 32) ? slds[wv][head * 64 + lane] : 0xFFFFFFFFu;
        }
    }
    if (lane < NK) {
        idx_out[row * NK + lane] = myidx;
        union { unsigned u; float f; } v; v.u = mykey;
        dist_out[row * NK + lane] = v.f;
    }
}

// ---------------- Precompute P = feats@W1a + b1, Q = feats@W1b (bf16, zero-padded) ----------------
__global__ __launch_bounds__(256) void pq_kernel(const float* __restrict__ feats,
                                                 const float* __restrict__ ew1,
                                                 const float* __restrict__ eb1,
                                                 short* __restrict__ P,
                                                 short* __restrict__ Q) {
    __shared__ float sf[4][ND];
    const int wv = threadIdx.x >> 6;
    const int lane = threadIdx.x & 63;
    const int gi = blockIdx.x * 4 + wv;
    sf[wv][lane] = feats[(size_t)gi * ND + lane];
    __syncthreads();
    float accP[5] = {0.f, 0.f, 0.f, 0.f, 0.f};
    float accQ[5] = {0.f, 0.f, 0.f, 0.f, 0.f};
    #pragma unroll 4
    for (int kx = 0; kx < ND; ++kx) {
        float a = sf[wv][kx];
        const float* wa = ew1 + (size_t)kx * EH + lane;
        const float* wb = ew1 + (size_t)(kx + 64) * EH + lane;
        #pragma unroll
        for (int t = 0; t < 5; ++t) {
            int c = lane + 64 * t;
            if (c < EH) {
                accP[t] += a * wa[64 * t];
                accQ[t] += a * wb[64 * t];
            }
        }
    }
    short* Pr = P + (size_t)gi * PQS;
    short* Qr = Q + (size_t)gi * PQS;
    #pragma unroll
    for (int t = 0; t < 5; ++t) {
        int c = lane + 64 * t;
        if (c < PQS) {
            Pr[c] = (c < EH) ? f2bf(accP[t] + eb1[c]) : (short)0;
            Qr[c] = (c < EH) ? f2bf(accQ[t]) : (short)0;
        }
    }
}

// ---------------- Edge: MFMA MLP2, m_i pooling, m_ij export. wave = 1 node ----------------
__global__ __launch_bounds__(256) void edge_kernel(
    const int* __restrict__ idx, const float* __restrict__ distk,
    const short* __restrict__ P, const short* __restrict__ Q,
    const float* __restrict__ w1pad, const short* __restrict__ W2T,
    const float* __restrict__ eb2,
    float* __restrict__ mi_out, short* __restrict__ mbuf) {
    const int tid = threadIdx.x;
    const int wv = tid >> 6, lane = tid & 63;
    const int er = lane & 15, grp = lane >> 4;
    const int gi = blockIdx.x * 4 + wv;      // node 0..8191
    const int b = gi >> 11;

    // B fragments: contiguous 16B loads from pre-transposed W2T[t=er][k]
    short8 bfrag[9];
    const short8* w2row = (const short8*)(W2T + er * PQS);
    #pragma unroll
    for (int kk = 0; kk < 9; ++kk) bfrag[kk] = w2row[kk * 4 + grp];

    const short8* Pr8 = (const short8*)(P + (size_t)gi * PQS);
    const f32x4* w14 = (const f32x4*)w1pad;

    f32x4 accT[2];
    #pragma unroll
    for (int T = 0; T < 2; ++T) {
        const int eA = T * 16 + er;                    // A-row edge
        const int jA = idx[gi * NK + eA];
        const float dA = distk[gi * NK + eA];
        const short8* Qr8 = (const short8*)(Q + (size_t)(b * NN + jA) * PQS);
        f32x4 acc = {0.f, 0.f, 0.f, 0.f};
        #pragma unroll
        for (int kk = 0; kk < 9; ++kk) {
            short8 pb = Pr8[kk * 4 + grp];
            short8 qb = Qr8[kk * 4 + grp];
            f32x4 w0 = w14[kk * 8 + grp * 2];
            f32x4 w1 = w14[kk * 8 + grp * 2 + 1];
            short8 af;
            #pragma unroll
            for (int i = 0; i < 4; ++i)
                af[i] = f2bf(silu_f(bf2f(pb[i]) + bf2f(qb[i]) + dA * w0[i]));
            #pragma unroll
            for (int i = 0; i < 4; ++i)
                af[4 + i] = f2bf(silu_f(bf2f(pb[4 + i]) + bf2f(qb[4 + i]) + dA * w1[i]));
            acc = __builtin_amdgcn_mfma_f32_16x16x32_bf16(af, bfrag[kk], acc, 0, 0, 0);
        }
        accT[T] = acc;
    }

    // lane holds m_pre[edge = T*16 + grp*4 + r][t = er]
    const float eb2v = eb2[er];
    float m0[4], m1[4];
    #pragma unroll
    for (int r = 0; r < 4; ++r) {
        m0[r] = silu_f(accT[0][r] + eb2v);
        m1[r] = silu_f(accT[1][r] + eb2v);
    }

    // m_i pooling over 32 edges for output t = er
    float s = m0[0] + m0[1] + m0[2] + m0[3] + m1[0] + m1[1] + m1[2] + m1[3];
    s += __shfl_xor(s, 16);
    s += __shfl_xor(s, 32);
    if (lane < NM) mi_out[gi * NM + er] = s;

    // export m_ij as bf16 [node][t][edge]
    short* mb = mbuf + (size_t)gi * (NM * NK) + er * NK;
    #pragma unroll
    for (int r = 0; r < 4; ++r) {
        mb[grp * 4 + r] = f2bf(m0[r]);
        mb[16 + grp * 4 + r] = f2bf(m1[r]);
    }
}

// ---------------- coors MLP + coordinate update: lane = edge ----------------
__global__ __launch_bounds__(256) void coors_kernel(
    const float* __restrict__ coors, const int* __restrict__ idx,
    const short* __restrict__ mbuf,
    const float* __restrict__ cw1, const float* __restrict__ cb1,
    const float* __restrict__ cw2, const float* __restrict__ cb2,
    float* __restrict__ coors_out) {
    const int tid = threadIdx.x;
    const int ge = blockIdx.x * 256 + tid;   // global edge 0..262143
    const int gi = ge >> 5, e = ge & 31;
    const int b = gi >> 11;
    const int j = idx[ge];
    const float ci0 = coors[gi * 3 + 0], ci1 = coors[gi * 3 + 1], ci2 = coors[gi * 3 + 2];
    const float* cj = coors + (size_t)(b * NN + j) * 3;
    const float rx = ci0 - cj[0], ry = ci1 - cj[1], rz = ci2 - cj[2];

    float m[16];
    const short* mb = mbuf + (size_t)gi * (NM * NK) + e;
    #pragma unroll
    for (int t = 0; t < 16; ++t) m[t] = bf2f(mb[t * NK]);

    float cwacc = cb2[0];
    #pragma unroll
    for (int c4 = 0; c4 < 4; ++c4) {         // 4 chunks of 16 hidden
        float a[16];
        #pragma unroll
        for (int u = 0; u < 16; ++u) a[u] = cb1[c4 * 16 + u];
        #pragma unroll
        for (int t = 0; t < 16; ++t) {
            const float* wr = cw1 + t * CHD + c4 * 16;
            #pragma unroll
            for (int u = 0; u < 16; ++u) a[u] += m[t] * wr[u];
        }
        #pragma unroll
        for (int u = 0; u < 16; ++u) cwacc += silu_f(a[u]) * cw2[c4 * 16 + u];
    }

    float wx = cwacc * rx, wy = cwacc * ry, wz = cwacc * rz;
    #pragma unroll
    for (int off = 1; off < 32; off <<= 1) {
        wx += __shfl_xor(wx, off);
        wy += __shfl_xor(wy, off);
        wz += __shfl_xor(wz, off);
    }
    if (e == 0) {
        coors_out[gi * 3 + 0] = ci0 + wx;
        coors_out[gi * 3 + 1] = ci1 + wy;
        coors_out[gi * 3 + 2] = ci2 + wz;
    }
}

// ---------------- Node MLP: wave per node ----------------
__global__ __launch_bounds__(256) void node_kernel(
    const float* __restrict__ feats, const float* __restrict__ mi,
    const float* __restrict__ nw1, const float* __restrict__ nb1,
    const float* __restrict__ nw2, const float* __restrict__ nb2,
    float* __restrict__ node_out) {
    __shared__ float hbuf[4][NHD];
    const int wv = threadIdx.x >> 6;
    const int lane = threadIdx.x & 63;
    const int gi = blockIdx.x * 4 + wv;
    const float* fi = feats + (size_t)gi * ND;
    float a0 = nb1[lane], a1 = nb1[64 + lane];
    #pragma unroll 4
    for (int k = 0; k < ND; ++k) {
        float a = fi[k];
        a0 += a * nw1[(size_t)k * NHD + lane];
        a1 += a * nw1[(size_t)k * NHD + 64 + lane];
    }
    #pragma unroll
    for (int k = 0; k < NM; ++k) {
        float a = mi[gi * NM + k];
        a0 += a * nw1[(size_t)(ND + k) * NHD + lane];
        a1 += a * nw1[(size_t)(ND + k) * NHD + 64 + lane];
    }
    hbuf[wv][lane] = silu_f(a0);
    hbuf[wv][64 + lane] = silu_f(a1);
    __syncthreads();
    float o = nb2[lane];
    #pragma unroll 4
    for (int k = 0; k < NHD; ++k) o += hbuf[wv][k] * nw2[(size_t)k * ND + lane];
    node_out[(size_t)gi * ND + lane] = o + fi[lane];
}

extern "C" void kernel_launch(void* const* d_in, const int* in_sizes, int n_in,
                              void* d_out, int out_size, void* d_ws, size_t ws_size,
                              hipStream_t stream) {
    const float* feats = (const float*)d_in[0];
    const float* coors = (const float*)d_in[1];
    const float* ew1 = (const float*)d_in[2];
    const float* eb1 = (const float*)d_in[3];
    const float* ew2 = (const float*)d_in[4];
    const float* eb2 = (const float*)d_in[5];
    const float* cw1 = (const float*)d_in[6];
    const float* cb1 = (const float*)d_in[7];
    const float* cw2 = (const float*)d_in[8];
    const float* cb2 = (const float*)d_in[9];
    const float* nw1 = (const float*)d_in[10];
    const float* nb1 = (const float*)d_in[11];
    const float* nw2 = (const float*)d_in[12];
    const float* nb2 = (const float*)d_in[13];

    float* out_node = (float*)d_out;                     // [4,2048,64]
    float* out_coors = out_node + (size_t)NB * NN * ND;  // [4,2048,3]

    char* ws = (char*)d_ws;
    int*   idx   = (int*)(ws + 0);             // 1,048,576 B
    float* distk = (float*)(ws + 1048576);     // 1,048,576 B
    float* mi    = (float*)(ws + 2097152);     //   524,288 B
    short* P     = (short*)(ws + 2621440);     // 4,718,592 B (bf16)
    short* Q     = (short*)(ws + 7340032);     // 4,718,592 B (bf16)
    short* mbuf  = (short*)(ws + 12058624);    // 8,388,608 B (bf16)
    float* w1pad = (float*)(ws + 20447232);    //     1,152 B
    short* W2T   = (short*)(ws + 20448384);    //     9,216 B

    prep_kernel<<<1, 256, 0, stream>>>(ew1, ew2, w1pad, W2T);
    knn_kernel<<<NB * NN / 4, 256, 0, stream>>>(coors, idx, distk);
    pq_kernel<<<NB * NN / 4, 256, 0, stream>>>(feats, ew1, eb1, P, Q);
    edge_kernel<<<NB * NN / 4, 256, 0, stream>>>(idx, distk, P, Q, w1pad, W2T, eb2, mi, mbuf);
    coors_kernel<<<NB * NN * NK / 256, 256, 0, stream>>>(coors, idx, mbuf, cw1, cb1, cw2, cb2, out_coors);
    node_kernel<<<NB * NN / 4, 256, 0, stream>>>(feats, mi, nw1, nb1, nw2, nb2, out_node);
}

// Round 5
// 122.035 us; speedup vs baseline: 4.9862x; 1.4604x over previous
//
#include <hip/hip_runtime.h>
#include <math.h>

#define NB 4
#define NN 2048
#define ND 64
#define NM 16
#define NK 32
#define EIN 129      // 2*ND+1
#define EH 258       // 2*EIN
#define CHD 64       // 4*NM
#define NHD 128      // 2*ND
#define PQS 288      // padded K for MFMA (zero-filled 258..287) = 9*32

typedef __attribute__((ext_vector_type(8))) short short8;
typedef __attribute__((ext_vector_type(4))) float f32x4;
typedef __attribute__((ext_vector_type(4))) int intx4;

__device__ __forceinline__ float fast_silu(float x) {
    return x * __builtin_amdgcn_rcpf(1.f + __expf(-x));
}

__device__ __forceinline__ short f2bf(float f) {   // RNE float->bf16
    union { float f; unsigned u; } v; v.f = f;
    unsigned r = v.u + 0x7FFFu + ((v.u >> 16) & 1u);
    return (short)(r >> 16);
}

__device__ __forceinline__ float bf2f(short s) {
    union { unsigned u; float f; } v;
    v.u = ((unsigned)(unsigned short)s) << 16;
    return v.f;
}

__device__ __forceinline__ unsigned cvt_pk_bf16(float lo, float hi) {
    unsigned r;
    asm("v_cvt_pk_bf16_f32 %0, %1, %2" : "=v"(r) : "v"(lo), "v"(hi));
    return r;
}

__device__ __forceinline__ unsigned umin_u(unsigned a, unsigned b) { return a < b ? a : b; }
__device__ __forceinline__ unsigned umax_u(unsigned a, unsigned b) { return a > b ? a : b; }

// ---------------- prep: pack weights ----------------
// blocks 0..71: W1F B-fragments; 72: w1pad+eb1pad; 73..88: W2T rows
__global__ void prep_kernel(const float* __restrict__ ew1, const float* __restrict__ ew2,
                            const float* __restrict__ eb1,
                            float* __restrict__ w1pad, float* __restrict__ eb1pad,
                            short* __restrict__ W2T, short* __restrict__ W1F) {
    const int tid = threadIdx.x;
    const int blk = blockIdx.x;
    if (blk < 72) {
        const int kk = blk & 1, ct = (blk >> 1) % 18, half = blk / 36;
        for (int t = tid; t < 512; t += 256) {
            const int l = t >> 3, i = t & 7;
            const int er = l & 15, grp = l >> 4;
            const int k = kk * 32 + grp * 8 + i;
            const int col = ct * 16 + er;
            const int row = half * 64 + k;
            W1F[blk * 512 + t] = (col < EH) ? f2bf(ew1[row * EH + col]) : (short)0;
        }
    } else if (blk == 72) {
        for (int c = tid; c < PQS; c += 256) {
            w1pad[c] = (c < EH) ? ew1[128 * EH + c] : 0.f;
            eb1pad[c] = (c < EH) ? eb1[c] : 0.f;
        }
    } else {
        const int t = blk - 73;
        for (int k = tid; k < PQS; k += 256)
            W2T[t * PQS + k] = (k < EH) ? f2bf(ew2[k * NM + t]) : (short)0;
    }
}

// ---------------- KNN: LDS-staged coors, bitonic sort, tournament ----------------
__global__ __launch_bounds__(256) void knn_kernel(const float* __restrict__ coors,
                                                  int* __restrict__ idx_out,
                                                  float* __restrict__ dist_out) {
    __shared__ union {
        float clds[NN * 3];
        unsigned slds[4][NN];
    } sm;
    const int wv = threadIdx.x >> 6;
    const int lane = threadIdx.x & 63;
    const int row0 = blockIdx.x * 4;
    const int b = row0 >> 11;
    const float* cb = coors + (size_t)b * NN * 3;
    for (int t = threadIdx.x; t < NN * 3; t += 256) sm.clds[t] = cb[t];
    __syncthreads();

    const int row = row0 + wv;
    const int i = row & (NN - 1);
    const float cix = sm.clds[i * 3 + 0], ciy = sm.clds[i * 3 + 1], ciz = sm.clds[i * 3 + 2];

    unsigned k[32];
    #pragma unroll
    for (int t = 0; t < 32; ++t) {
        int j = lane + 64 * t;
        float dx = cix - sm.clds[j * 3 + 0];
        float dy = ciy - sm.clds[j * 3 + 1];
        float dz = ciz - sm.clds[j * 3 + 2];
        float d = dx * dx + dy * dy + dz * dz;
        union { float f; unsigned u; } v; v.f = d;
        k[t] = (v.u & 0xFFFFF800u) | (unsigned)j;
    }
    __syncthreads();   // all clds reads done before slds overwrite

    // in-register bitonic sort: up is constant-folded -> pure v_min/v_max
    #pragma unroll
    for (int size = 2; size <= 32; size <<= 1) {
        #pragma unroll
        for (int stride = size >> 1; stride > 0; stride >>= 1) {
            #pragma unroll
            for (int t = 0; t < 32; ++t) {
                int p = t ^ stride;
                if (p > t) {
                    const bool up = ((t & size) == 0);
                    unsigned lo = umin_u(k[t], k[p]);
                    unsigned hi = umax_u(k[t], k[p]);
                    k[t] = up ? lo : hi;
                    k[p] = up ? hi : lo;
                }
            }
        }
    }
    #pragma unroll
    for (int t = 0; t < 32; ++t) sm.slds[wv][t * 64 + lane] = k[t];

    unsigned cur = k[0];
    int head = 0;
    int myidx = 0;
    unsigned mykey = 0;
    for (int it = 0; it < NK; ++it) {
        unsigned w = cur;
        #pragma unroll
        for (int off = 1; off < 64; off <<= 1) {
            unsigned o = __shfl_xor(w, off);
            w = umin_u(w, o);
        }
        if (lane == it) { myidx = (int)(w & 2047u); mykey = w & 0xFFFFF800u; }
        if (cur == w) {
            ++head;
            cur = (head < 32) ? sm.slds[wv][head * 64 + lane] : 0xFFFFFFFFu;
        }
    }
    if (lane < NK) {
        idx_out[row * NK + lane] = myidx;
        union { unsigned u; float f; } v; v.u = mykey;
        dist_out[row * NK + lane] = v.f;
    }
}

// ---------------- pq: MFMA GEMM. wave = (mtile 16 nodes, ctile 16 cols), P+Q ----------------
__global__ __launch_bounds__(256) void pq_kernel(const float* __restrict__ feats,
                                                 const short* __restrict__ W1F,
                                                 const float* __restrict__ eb1pad,
                                                 short* __restrict__ P,
                                                 short* __restrict__ Q) {
    const int wv = threadIdx.x >> 6, lane = threadIdx.x & 63;
    const int er = lane & 15, grp = lane >> 4;
    const int wid = blockIdx.x * 4 + wv;      // 0..9215
    const int mt = wid / 18, ct = wid % 18;
    const int nb = mt * 16;

    // A fragments: feats rows nb+er, k = kk*32 + grp*8 + i
    short8 a[2];
    #pragma unroll
    for (int kk = 0; kk < 2; ++kk) {
        const float* fp = feats + (size_t)(nb + er) * ND + kk * 32 + grp * 8;
        f32x4 f0 = *(const f32x4*)fp;
        f32x4 f1 = *(const f32x4*)(fp + 4);
        union { intx4 iv; short8 s; } u;
        u.iv[0] = cvt_pk_bf16(f0[0], f0[1]);
        u.iv[1] = cvt_pk_bf16(f0[2], f0[3]);
        u.iv[2] = cvt_pk_bf16(f1[0], f1[1]);
        u.iv[3] = cvt_pk_bf16(f1[2], f1[3]);
        a[kk] = u.s;
    }

    // B fragments from packed W1F: frag id = (half*18 + ct)*2 + kk
    const short8* WF = (const short8*)W1F;
    short8 bP0 = WF[((0 * 18 + ct) * 2 + 0) * 64 + lane];
    short8 bP1 = WF[((0 * 18 + ct) * 2 + 1) * 64 + lane];
    short8 bQ0 = WF[((1 * 18 + ct) * 2 + 0) * 64 + lane];
    short8 bQ1 = WF[((1 * 18 + ct) * 2 + 1) * 64 + lane];

    f32x4 accP = {0.f, 0.f, 0.f, 0.f};
    f32x4 accQ = {0.f, 0.f, 0.f, 0.f};
    accP = __builtin_amdgcn_mfma_f32_16x16x32_bf16(a[0], bP0, accP, 0, 0, 0);
    accP = __builtin_amdgcn_mfma_f32_16x16x32_bf16(a[1], bP1, accP, 0, 0, 0);
    accQ = __builtin_amdgcn_mfma_f32_16x16x32_bf16(a[0], bQ0, accQ, 0, 0, 0);
    accQ = __builtin_amdgcn_mfma_f32_16x16x32_bf16(a[1], bQ1, accQ, 0, 0, 0);

    const float bias = eb1pad[ct * 16 + er];
    #pragma unroll
    for (int r = 0; r < 4; ++r) {
        const int node = nb + grp * 4 + r;
        P[(size_t)node * PQS + ct * 16 + er] = f2bf(accP[r] + bias);
        Q[(size_t)node * PQS + ct * 16 + er] = f2bf(accQ[r]);
    }
}

// ---------------- Edge: MFMA MLP2, m_i pooling, m_ij export. wave = 1 node ----------------
__global__ __launch_bounds__(256) void edge_kernel(
    const int* __restrict__ idx, const float* __restrict__ distk,
    const short* __restrict__ P, const short* __restrict__ Q,
    const float* __restrict__ w1pad, const short* __restrict__ W2T,
    const float* __restrict__ eb2,
    float* __restrict__ mi_out, short* __restrict__ mbuf) {
    const int tid = threadIdx.x;
    const int wv = tid >> 6, lane = tid & 63;
    const int er = lane & 15, grp = lane >> 4;
    const int gi = blockIdx.x * 4 + wv;      // node 0..8191
    const int b = gi >> 11;

    short8 bfrag[9];
    const short8* w2row = (const short8*)(W2T + er * PQS);
    #pragma unroll
    for (int kk = 0; kk < 9; ++kk) bfrag[kk] = w2row[kk * 4 + grp];

    const short8* Pr8 = (const short8*)(P + (size_t)gi * PQS);
    const f32x4* w14 = (const f32x4*)w1pad;

    f32x4 accT[2];
    #pragma unroll
    for (int T = 0; T < 2; ++T) {
        const int eA = T * 16 + er;
        const int jA = idx[gi * NK + eA];
        const float dA = distk[gi * NK + eA];
        const short8* Qr8 = (const short8*)(Q + (size_t)(b * NN + jA) * PQS);
        f32x4 acc = {0.f, 0.f, 0.f, 0.f};
        #pragma unroll
        for (int kk = 0; kk < 9; ++kk) {
            short8 pb = Pr8[kk * 4 + grp];
            short8 qb = Qr8[kk * 4 + grp];
            f32x4 w0 = w14[kk * 8 + grp * 2];
            f32x4 w1 = w14[kk * 8 + grp * 2 + 1];
            float h[8];
            #pragma unroll
            for (int i = 0; i < 4; ++i)
                h[i] = fast_silu(bf2f(pb[i]) + bf2f(qb[i]) + dA * w0[i]);
            #pragma unroll
            for (int i = 0; i < 4; ++i)
                h[4 + i] = fast_silu(bf2f(pb[4 + i]) + bf2f(qb[4 + i]) + dA * w1[i]);
            union { intx4 iv; short8 s; } u;
            u.iv[0] = cvt_pk_bf16(h[0], h[1]);
            u.iv[1] = cvt_pk_bf16(h[2], h[3]);
            u.iv[2] = cvt_pk_bf16(h[4], h[5]);
            u.iv[3] = cvt_pk_bf16(h[6], h[7]);
            acc = __builtin_amdgcn_mfma_f32_16x16x32_bf16(u.s, bfrag[kk], acc, 0, 0, 0);
        }
        accT[T] = acc;
    }

    // lane holds m_pre[edge = T*16 + grp*4 + r][t = er]
    const float eb2v = eb2[er];
    float m0[4], m1[4];
    #pragma unroll
    for (int r = 0; r < 4; ++r) {
        m0[r] = fast_silu(accT[0][r] + eb2v);
        m1[r] = fast_silu(accT[1][r] + eb2v);
    }

    // m_i pooling over 32 edges for output t = er
    float s = m0[0] + m0[1] + m0[2] + m0[3] + m1[0] + m1[1] + m1[2] + m1[3];
    s += __shfl_xor(s, 16);
    s += __shfl_xor(s, 32);
    if (lane < NM) mi_out[gi * NM + er] = s;

    // export m_ij bf16, layout [node][edge][t]
    short* mb = mbuf + (size_t)gi * (NK * NM);
    #pragma unroll
    for (int r = 0; r < 4; ++r) {
        mb[(grp * 4 + r) * NM + er] = f2bf(m0[r]);
        mb[(16 + grp * 4 + r) * NM + er] = f2bf(m1[r]);
    }
}

// ---------------- coors MLP + coordinate update: lane = edge ----------------
__global__ __launch_bounds__(256) void coors_kernel(
    const float* __restrict__ coors, const int* __restrict__ idx,
    const short* __restrict__ mbuf,
    const float* __restrict__ cw1, const float* __restrict__ cb1,
    const float* __restrict__ cw2, const float* __restrict__ cb2,
    float* __restrict__ coors_out) {
    const int tid = threadIdx.x;
    const int ge = blockIdx.x * 256 + tid;   // global edge
    const int gi = ge >> 5, e = ge & 31;
    const int b = gi >> 11;
    const int j = idx[ge];
    const float ci0 = coors[gi * 3 + 0], ci1 = coors[gi * 3 + 1], ci2 = coors[gi * 3 + 2];
    const float* cj = coors + (size_t)(b * NN + j) * 3;
    const float rx = ci0 - cj[0], ry = ci1 - cj[1], rz = ci2 - cj[2];

    const short8* mv = (const short8*)(mbuf + (size_t)gi * (NK * NM) + e * NM);
    short8 ma = mv[0], mb2 = mv[1];
    float m[16];
    #pragma unroll
    for (int i = 0; i < 8; ++i) { m[i] = bf2f(ma[i]); m[8 + i] = bf2f(mb2[i]); }

    float cwacc = cb2[0];
    #pragma unroll
    for (int c4 = 0; c4 < 4; ++c4) {
        float a[16];
        #pragma unroll
        for (int u = 0; u < 16; ++u) a[u] = cb1[c4 * 16 + u];
        #pragma unroll
        for (int t = 0; t < 16; ++t) {
            const float* wr = cw1 + t * CHD + c4 * 16;
            #pragma unroll
            for (int u = 0; u < 16; ++u) a[u] += m[t] * wr[u];
        }
        #pragma unroll
        for (int u = 0; u < 16; ++u) cwacc += fast_silu(a[u]) * cw2[c4 * 16 + u];
    }

    float wx = cwacc * rx, wy = cwacc * ry, wz = cwacc * rz;
    #pragma unroll
    for (int off = 1; off < 32; off <<= 1) {
        wx += __shfl_xor(wx, off);
        wy += __shfl_xor(wy, off);
        wz += __shfl_xor(wz, off);
    }
    if (e == 0) {
        coors_out[gi * 3 + 0] = ci0 + wx;
        coors_out[gi * 3 + 1] = ci1 + wy;
        coors_out[gi * 3 + 2] = ci2 + wz;
    }
}

// ---------------- Node MLP: wave per node ----------------
__global__ __launch_bounds__(256) void node_kernel(
    const float* __restrict__ feats, const float* __restrict__ mi,
    const float* __restrict__ nw1, const float* __restrict__ nb1,
    const float* __restrict__ nw2, const float* __restrict__ nb2,
    float* __restrict__ node_out) {
    __shared__ float hbuf[4][NHD];
    const int wv = threadIdx.x >> 6;
    const int lane = threadIdx.x & 63;
    const int gi = blockIdx.x * 4 + wv;
    const float* fi = feats + (size_t)gi * ND;
    float a0 = nb1[lane], a1 = nb1[64 + lane];
    #pragma unroll 4
    for (int k = 0; k < ND; ++k) {
        float a = fi[k];
        a0 += a * nw1[(size_t)k * NHD + lane];
        a1 += a * nw1[(size_t)k * NHD + 64 + lane];
    }
    #pragma unroll
    for (int k = 0; k < NM; ++k) {
        float a = mi[gi * NM + k];
        a0 += a * nw1[(size_t)(ND + k) * NHD + lane];
        a1 += a * nw1[(size_t)(ND + k) * NHD + 64 + lane];
    }
    hbuf[wv][lane] = fast_silu(a0);
    hbuf[wv][64 + lane] = fast_silu(a1);
    __syncthreads();
    float o = nb2[lane];
    #pragma unroll 4
    for (int k = 0; k < NHD; ++k) o += hbuf[wv][k] * nw2[(size_t)k * ND + lane];
    node_out[(size_t)gi * ND + lane] = o + fi[lane];
}

extern "C" void kernel_launch(void* const* d_in, const int* in_sizes, int n_in,
                              void* d_out, int out_size, void* d_ws, size_t ws_size,
                              hipStream_t stream) {
    const float* feats = (const float*)d_in[0];
    const float* coors = (const float*)d_in[1];
    const float* ew1 = (const float*)d_in[2];
    const float* eb1 = (const float*)d_in[3];
    const float* ew2 = (const float*)d_in[4];
    const float* eb2 = (const float*)d_in[5];
    const float* cw1 = (const float*)d_in[6];
    const float* cb1 = (const float*)d_in[7];
    const float* cw2 = (const float*)d_in[8];
    const float* cb2 = (const float*)d_in[9];
    const float* nw1 = (const float*)d_in[10];
    const float* nb1 = (const float*)d_in[11];
    const float* nw2 = (const float*)d_in[12];
    const float* nb2 = (const float*)d_in[13];

    float* out_node = (float*)d_out;                     // [4,2048,64]
    float* out_coors = out_node + (size_t)NB * NN * ND;  // [4,2048,3]

    char* ws = (char*)d_ws;
    int*   idx    = (int*)(ws + 0);             // 1,048,576
    float* distk  = (float*)(ws + 1048576);     // 1,048,576
    float* mi     = (float*)(ws + 2097152);     //   524,288
    short* P      = (short*)(ws + 2621440);     // 4,718,592 (bf16)
    short* Q      = (short*)(ws + 7340032);     // 4,718,592 (bf16)
    short* mbuf   = (short*)(ws + 12058624);    // 8,388,608 (bf16)
    float* w1pad  = (float*)(ws + 20447232);    //     1,152
    float* eb1pad = (float*)(ws + 20448384);    //     1,152
    short* W2T    = (short*)(ws + 20449536);    //     9,216
    short* W1F    = (short*)(ws + 20458752);    //    73,728

    prep_kernel<<<89, 256, 0, stream>>>(ew1, ew2, eb1, w1pad, eb1pad, W2T, W1F);
    knn_kernel<<<NB * NN / 4, 256, 0, stream>>>(coors, idx, distk);
    pq_kernel<<<(512 * 18) / 4, 256, 0, stream>>>(feats, W1F, eb1pad, P, Q);
    edge_kernel<<<NB * NN / 4, 256, 0, stream>>>(idx, distk, P, Q, w1pad, W2T, eb2, mi, mbuf);
    coors_kernel<<<NB * NN * NK / 256, 256, 0, stream>>>(coors, idx, mbuf, cw1, cb1, cw2, cb2, out_coors);
    node_kernel<<<NB * NN / 4, 256, 0, stream>>>(feats, mi, nw1, nb1, nw2, nb2, out_node);
}